// Round 3
// baseline (191.748 us; speedup 1.0000x reference)
//
#include <hip/hip_runtime.h>
#include <hip/hip_bf16.h>
#include <math.h>

// MultiHeadAttentionQuantum, B=2048 S=1 E=1024 H=128 DK=NW=8
// All inputs/outputs float32.
//
// Algebra: S==1 -> attention out == v = x @ Wv^T (wq,wk dead).
// RX compose additively; CNOTs are XOR basis permutations ->
//   t_j = cos(v_j + rx_j);  qout[0]=t1..t7;  qout[w>=1]=t0..tw
// out = qout @ Wc^T + bc
//
// R2 post-mortem: GEMMs latency-bound (MfmaUtil 2.5%, VALUBusy 5%, 2 waves/SIMD).
// R3: bf16 weights (pre-converted in ws), 512-thread blocks (4 waves/SIMD),
//     depth-2 register prefetch pipeline, quantum fused into gemm1 epilogue.

#define BN 2048
#define EN 1024

typedef short s16x8 __attribute__((ext_vector_type(8)));
typedef float f32x4 __attribute__((ext_vector_type(4)));

union Frag { s16x8 v; __hip_bfloat16 h[8]; };

__device__ inline s16x8 cvt_frag(f32x4 lo, f32x4 hi) {
    Frag u;
    #pragma unroll
    for (int j = 0; j < 4; ++j) {
        u.h[j]     = __float2bfloat16(lo[j]);
        u.h[4 + j] = __float2bfloat16(hi[j]);
    }
    return u.v;
}

// Convert wv, wc (f32, 1M elems each) -> bf16 in ws. 8 elems/thread.
__global__ __launch_bounds__(256) void cvt_kernel(
        const float* __restrict__ wv, const float* __restrict__ wc,
        __hip_bfloat16* __restrict__ wvb, __hip_bfloat16* __restrict__ wcb)
{
    const int g = blockIdx.x * 256 + threadIdx.x;      // 0 .. 262143
    const int NG = (EN * EN) / 8;                      // 131072 groups per matrix
    const float* src = (g < NG) ? wv : wc;
    __hip_bfloat16* dst = (g < NG) ? wvb : wcb;
    const size_t off = (size_t)((g < NG) ? g : g - NG) * 8;
    f32x4 lo = *(const f32x4*)(src + off);
    f32x4 hi = *(const f32x4*)(src + off + 4);
    *(s16x8*)(dst + off) = cvt_frag(lo, hi);
}

// Unified GEMM: C-op[m,n] = sum_k A[m,k]*W[n,k]
// block tile 64x64, 512 threads = 8 waves in 2(m) x 4(n) grid, wave tile 32x16.
// mfma_f32_16x16x32_bf16: A[m=lane&15][k=(lane>>4)*8+j]; C/D col=lane&15,row=(lane>>4)*4+r.
// AF32: A is f32 (cvt at consume). BF32: W is f32 (fallback when ws too small).
// EPI 0: quantum epilogue -> bf16 V (uses rx).  EPI 1: +bias -> f32 out.
template <bool AF32, bool BF32, int EPI>
__global__ __launch_bounds__(512, 4) void gemm_kernel(
        const void* __restrict__ Av, const void* __restrict__ Wv_,
        const float* __restrict__ rx, const float* __restrict__ bias,
        void* __restrict__ Cv)
{
    const int tid  = threadIdx.x;
    const int wave = tid >> 6, lane = tid & 63;
    const int l15 = lane & 15, lq = lane >> 4;
    const int m0 = blockIdx.x * 64, n0 = blockIdx.y * 64;
    const int wm = (wave & 1) * 32;        // wave m-offset in block tile
    const int wn = (wave >> 1) * 16;       // wave n-offset

    // A base pointers (two 16-row frags)
    const float* paf0 = (const float*)Av + (size_t)(m0 + wm + l15) * EN + lq * 8;
    const float* paf1 = paf0 + 16 * EN;
    const __hip_bfloat16* pab0 = (const __hip_bfloat16*)Av + (size_t)(m0 + wm + l15) * EN + lq * 8;
    const __hip_bfloat16* pab1 = pab0 + 16 * EN;
    // B base pointer (one 16-col frag)
    const float* pbf = (const float*)Wv_ + (size_t)(n0 + wn + l15) * EN + lq * 8;
    const __hip_bfloat16* pbb = (const __hip_bfloat16*)Wv_ + (size_t)(n0 + wn + l15) * EN + lq * 8;

    f32x4 acc0 = {0.f, 0.f, 0.f, 0.f}, acc1 = {0.f, 0.f, 0.f, 0.f};

    struct Set {
        f32x4 a0l, a0h, a1l, a1h;   // AF32 raw
        s16x8 a0b, a1b;             // !AF32
        f32x4 b0l, b0h;             // BF32 raw
        s16x8 bb;                   // !BF32
    };
    auto loadSet = [&](int k) {
        Set s;
        if (AF32) {
            s.a0l = *(const f32x4*)(paf0 + k);  s.a0h = *(const f32x4*)(paf0 + k + 4);
            s.a1l = *(const f32x4*)(paf1 + k);  s.a1h = *(const f32x4*)(paf1 + k + 4);
        } else {
            s.a0b = *(const s16x8*)(pab0 + k);  s.a1b = *(const s16x8*)(pab1 + k);
        }
        if (BF32) {
            s.b0l = *(const f32x4*)(pbf + k);   s.b0h = *(const f32x4*)(pbf + k + 4);
        } else {
            s.bb  = *(const s16x8*)(pbb + k);
        }
        return s;
    };
    auto consume = [&](const Set& s) {
        s16x8 a0 = AF32 ? cvt_frag(s.a0l, s.a0h) : s.a0b;
        s16x8 a1 = AF32 ? cvt_frag(s.a1l, s.a1h) : s.a1b;
        s16x8 b  = BF32 ? cvt_frag(s.b0l, s.b0h) : s.bb;
        acc0 = __builtin_amdgcn_mfma_f32_16x16x32_bf16(a0, b, acc0, 0, 0, 0);
        acc1 = __builtin_amdgcn_mfma_f32_16x16x32_bf16(a1, b, acc1, 0, 0, 0);
    };

    // depth-2 software pipeline over 32 K-chunks of 32
    Set s0 = loadSet(0), s1 = loadSet(32);
    for (int k = 64; k < EN; k += 64) {
        Set t0 = loadSet(k);
        consume(s0);
        Set t1 = loadSet(k + 32);
        consume(s1);
        s0 = t0; s1 = t1;
    }
    consume(s0); consume(s1);

    if (EPI == 0) {
        // quantum epilogue: acc -> LDS (row-major, pad 68), 8-col head groups
        __shared__ float sb[64 * 68];
        const int col = wn + l15;
        #pragma unroll
        for (int r = 0; r < 4; ++r) {
            sb[(wm +      lq * 4 + r) * 68 + col] = acc0[r];
            sb[(wm + 16 + lq * 4 + r) * 68 + col] = acc1[r];
        }
        __syncthreads();
        const int row = tid >> 3;            // 0..63
        const int gc  = (tid & 7) * 8;       // head-group col
        const float* g = &sb[row * 68 + gc];
        float t[8];
        #pragma unroll
        for (int j = 0; j < 8; ++j) t[j] = __cosf(g[j] + rx[j]);
        Frag o;
        float suf = t[1];
        #pragma unroll
        for (int j = 2; j < 8; ++j) suf *= t[j];
        o.h[0] = __float2bfloat16(suf);
        float p = t[0];
        #pragma unroll
        for (int j = 1; j < 8; ++j) { p *= t[j]; o.h[j] = __float2bfloat16(p); }
        __hip_bfloat16* V = (__hip_bfloat16*)Cv;
        *(s16x8*)(V + (size_t)(m0 + row) * EN + n0 + gc) = o.v;
    } else {
        float* C = (float*)Cv;
        const int col = n0 + wn + l15;
        const float b = bias[col];
        #pragma unroll
        for (int r = 0; r < 4; ++r) {
            C[(size_t)(m0 + wm +      lq * 4 + r) * EN + col] = acc0[r] + b;
            C[(size_t)(m0 + wm + 16 + lq * 4 + r) * EN + col] = acc1[r] + b;
        }
    }
}

extern "C" void kernel_launch(void* const* d_in, const int* in_sizes, int n_in,
                              void* d_out, int out_size, void* d_ws, size_t ws_size,
                              hipStream_t stream)
{
    // inputs: x, wq, wk, wv, wc, bc, rx_params (wq/wk dead: S==1)
    const float* x  = (const float*)d_in[0];
    const float* wv = (const float*)d_in[3];
    const float* wc = (const float*)d_in[4];
    const float* bc = (const float*)d_in[5];
    const float* rx = (const float*)d_in[6];
    float* out = (float*)d_out;

    const size_t WB = (size_t)EN * EN * sizeof(__hip_bfloat16);   // 2 MB
    const size_t VB = (size_t)BN * EN * sizeof(__hip_bfloat16);   // 4 MB
    dim3 grid(BN / 64, EN / 64);                                  // 32 x 16

    if (ws_size >= 2 * WB + VB) {
        // bf16-weight path: ws = [wvb 2MB | wcb 2MB | V 4MB]
        __hip_bfloat16* wvb = (__hip_bfloat16*)d_ws;
        __hip_bfloat16* wcb = wvb + (size_t)EN * EN;
        __hip_bfloat16* V   = wcb + (size_t)EN * EN;
        cvt_kernel<<<(2 * EN * EN / 8) / 256, 256, 0, stream>>>(wv, wc, wvb, wcb);
        gemm_kernel<true,  false, 0><<<grid, 512, 0, stream>>>(x, wvb, rx, nullptr, V);
        gemm_kernel<false, false, 1><<<grid, 512, 0, stream>>>(V, wcb, nullptr, bc, out);
    } else {
        // fallback: ws = [V 4MB]; weights loaded f32 in-loop
        __hip_bfloat16* V = (__hip_bfloat16*)d_ws;
        gemm_kernel<true,  true, 0><<<grid, 512, 0, stream>>>(x, wv, rx, nullptr, V);
        gemm_kernel<false, true, 1><<<grid, 512, 0, stream>>>(V, wc, nullptr, bc, out);
    }
}

// Round 4
// 115.536 us; speedup vs baseline: 1.6596x; 1.6596x over previous
//
#include <hip/hip_runtime.h>
#include <hip/hip_bf16.h>
#include <math.h>

// MultiHeadAttentionQuantum, B=2048 S=1 E=1024 H=128 DK=NW=8
// All inputs/outputs float32.
//
// Algebra: S==1 -> attention out == v = x @ Wv^T (wq,wk dead).
// RX compose additively; CNOTs are XOR basis permutations ->
//   t_j = cos(v_j + rx_j);  qout[0]=t1*...*t7;  qout[w>=1]=t0*...*tw
// out = qout @ Wc^T + bc
//
// R3 post-mortem: register software-pipeline collapsed by compiler (VGPR=36),
// loads serialized, MfmaUtil 2%. R4: m93-style LDS-staged GEMM:
// BM=128 BN=64 BK=32, 256 thr, wave tile 64x32, padded LDS (stride 40),
// bulk b128 staging with depth-1 register prefetch across the barrier.

#define BB 2048
#define EN 1024
#define LDA 40   // padded LDS row stride (elems)

typedef short s16x8 __attribute__((ext_vector_type(8)));
typedef float f32x4 __attribute__((ext_vector_type(4)));

union Frag { s16x8 v; __hip_bfloat16 h[8]; };

__device__ inline s16x8 cvt_frag(f32x4 lo, f32x4 hi) {
    Frag u;
    #pragma unroll
    for (int j = 0; j < 4; ++j) {
        u.h[j]     = __float2bfloat16(lo[j]);
        u.h[4 + j] = __float2bfloat16(hi[j]);
    }
    return u.v;
}

// Convert x (nx groups of 8), wv, wc (131072 groups each) -> bf16.
__global__ __launch_bounds__(256) void cvt3_kernel(
        const float* __restrict__ x, const float* __restrict__ wv,
        const float* __restrict__ wc,
        __hip_bfloat16* __restrict__ xb, __hip_bfloat16* __restrict__ wvb,
        __hip_bfloat16* __restrict__ wcb, int nx)
{
    const int g = blockIdx.x * 256 + threadIdx.x;
    const int NG = (EN * EN) / 8;                  // 131072
    const float* s; __hip_bfloat16* d; size_t off;
    if (g < nx)           { s = x;  d = xb;  off = (size_t)g * 8; }
    else if (g < nx + NG) { s = wv; d = wvb; off = (size_t)(g - nx) * 8; }
    else                  { s = wc; d = wcb; off = (size_t)(g - nx - NG) * 8; }
    f32x4 lo = *(const f32x4*)(s + off);
    f32x4 hi = *(const f32x4*)(s + off + 4);
    *(s16x8*)(d + off) = cvt_frag(lo, hi);
}

// GEMM: C[m,n] = sum_k A[m,k] * W[n,k].  A: 2048xEN, W: ENxEN (K-contiguous).
// AF32: A is f32, converted during staging. EPI 0: bf16 store. EPI 1: f32+bias.
// mfma_f32_16x16x32_bf16: A[m=lane&15][k=(lane>>4)*8+j]; C/D col=lane&15,
// row=(lane>>4)*4+r.
template <bool AF32, int EPI>
__global__ __launch_bounds__(256, 4) void gemm_kernel(
        const void* __restrict__ Av, const __hip_bfloat16* __restrict__ Wb,
        const float* __restrict__ bias, void* __restrict__ Cv)
{
    __shared__ __hip_bfloat16 As[128 * LDA];   // 10 KB
    __shared__ __hip_bfloat16 Bs[64 * LDA];    // 5 KB

    const int tid  = threadIdx.x;
    const int wave = tid >> 6, lane = tid & 63;
    const int l15 = lane & 15, lq = lane >> 4;
    const int m0 = blockIdx.x * 128, n0 = blockIdx.y * 64;
    const int wm = (wave & 1) * 64, wn = (wave >> 1) * 32;

    // staging: thread covers 8 contiguous k-elems of row sr (+64 for 2nd A half)
    const int sr = tid >> 2;            // 0..63
    const int sk = (tid & 3) * 8;       // 0,8,16,24
    const float*          af = (const float*)Av;
    const __hip_bfloat16* ab = (const __hip_bfloat16*)Av;
    __hip_bfloat16* aw0 = &As[sr * LDA + sk];
    __hip_bfloat16* aw1 = &As[(sr + 64) * LDA + sk];
    __hip_bfloat16* bw  = &Bs[sr * LDA + sk];

    auto g_load = [&](int kk, s16x8& ra0, s16x8& ra1, s16x8& rb) {
        if (AF32) {
            const float* p0 = af + (size_t)(m0 + sr) * EN + kk + sk;
            const float* p1 = p0 + (size_t)64 * EN;
            ra0 = cvt_frag(*(const f32x4*)p0, *(const f32x4*)(p0 + 4));
            ra1 = cvt_frag(*(const f32x4*)p1, *(const f32x4*)(p1 + 4));
        } else {
            const __hip_bfloat16* p0 = ab + (size_t)(m0 + sr) * EN + kk + sk;
            ra0 = *(const s16x8*)p0;
            ra1 = *(const s16x8*)(p0 + (size_t)64 * EN);
        }
        rb = *(const s16x8*)(Wb + (size_t)(n0 + sr) * EN + kk + sk);
    };

    f32x4 acc[4][2] = {};

    s16x8 ra0, ra1, rb;
    g_load(0, ra0, ra1, rb);
    *(s16x8*)aw0 = ra0; *(s16x8*)aw1 = ra1; *(s16x8*)bw = rb;
    __syncthreads();

    for (int kk = 32; kk <= EN; kk += 32) {
        const bool more = (kk < EN);
        s16x8 na0, na1, nb;
        if (more) g_load(kk, na0, na1, nb);

        s16x8 a[4], b[2];
        #pragma unroll
        for (int i = 0; i < 4; ++i)
            a[i] = *(const s16x8*)&As[(wm + 16 * i + l15) * LDA + lq * 8];
        #pragma unroll
        for (int j = 0; j < 2; ++j)
            b[j] = *(const s16x8*)&Bs[(wn + 16 * j + l15) * LDA + lq * 8];
        #pragma unroll
        for (int i = 0; i < 4; ++i)
            #pragma unroll
            for (int j = 0; j < 2; ++j)
                acc[i][j] = __builtin_amdgcn_mfma_f32_16x16x32_bf16(
                                a[i], b[j], acc[i][j], 0, 0, 0);

        __syncthreads();
        if (more) {
            *(s16x8*)aw0 = na0; *(s16x8*)aw1 = na1; *(s16x8*)bw = nb;
        }
        __syncthreads();
    }

    if (EPI == 0) {
        __hip_bfloat16* C = (__hip_bfloat16*)Cv;
        #pragma unroll
        for (int i = 0; i < 4; ++i)
            #pragma unroll
            for (int j = 0; j < 2; ++j) {
                const int col = n0 + wn + 16 * j + l15;
                #pragma unroll
                for (int r = 0; r < 4; ++r) {
                    const int row = m0 + wm + 16 * i + lq * 4 + r;
                    C[(size_t)row * EN + col] = __float2bfloat16(acc[i][j][r]);
                }
            }
    } else {
        float* C = (float*)Cv;
        #pragma unroll
        for (int j = 0; j < 2; ++j) {
            const int col = n0 + wn + 16 * j + l15;
            const float bv = bias[col];
            #pragma unroll
            for (int i = 0; i < 4; ++i)
                #pragma unroll
                for (int r = 0; r < 4; ++r) {
                    const int row = m0 + wm + 16 * i + lq * 4 + r;
                    C[(size_t)row * EN + col] = acc[i][j][r] + bv;
                }
        }
    }
}

// One thread per (b,h) group of 8 angles; in-place on V (bf16).
__global__ __launch_bounds__(256) void quantum_kernel(
        __hip_bfloat16* __restrict__ V, const float* __restrict__ rx)
{
    const int g = blockIdx.x * 256 + threadIdx.x;   // exact grid: BB*EN/8
    Frag in;
    in.v = *(const s16x8*)(V + (size_t)g * 8);
    float t[8];
    #pragma unroll
    for (int j = 0; j < 8; ++j)
        t[j] = cosf(__bfloat162float(in.h[j]) + rx[j]);

    Frag o;
    float suf = t[1];
    #pragma unroll
    for (int j = 2; j < 8; ++j) suf *= t[j];
    o.h[0] = __float2bfloat16(suf);
    float p = t[0];
    #pragma unroll
    for (int j = 1; j < 8; ++j) { p *= t[j]; o.h[j] = __float2bfloat16(p); }

    *(s16x8*)(V + (size_t)g * 8) = o.v;
}

extern "C" void kernel_launch(void* const* d_in, const int* in_sizes, int n_in,
                              void* d_out, int out_size, void* d_ws, size_t ws_size,
                              hipStream_t stream)
{
    // inputs: x, wq, wk, wv, wc, bc, rx_params (wq/wk dead: S==1)
    const float* x  = (const float*)d_in[0];
    const float* wv = (const float*)d_in[3];
    const float* wc = (const float*)d_in[4];
    const float* bc = (const float*)d_in[5];
    const float* rx = (const float*)d_in[6];
    float* out = (float*)d_out;

    const size_t XE = (size_t)BB * EN;   // 2M elems
    const size_t WE = (size_t)EN * EN;   // 1M elems
    dim3 grid(BB / 128, EN / 64);        // 16 x 16 = 256 blocks

    if (ws_size >= (XE + 2 * WE + XE) * sizeof(__hip_bfloat16)) {   // 12 MB
        __hip_bfloat16* xb  = (__hip_bfloat16*)d_ws;
        __hip_bfloat16* wvb = xb + XE;
        __hip_bfloat16* wcb = wvb + WE;
        __hip_bfloat16* V   = wcb + WE;
        cvt3_kernel<<<(int)((XE / 8 + 2 * (WE / 8)) / 256), 256, 0, stream>>>(
            x, wv, wc, xb, wvb, wcb, (int)(XE / 8));
        gemm_kernel<false, 0><<<grid, 256, 0, stream>>>(xb, wvb, nullptr, V);
        quantum_kernel<<<(int)(XE / 8 / 256), 256, 0, stream>>>(V, rx);
        gemm_kernel<false, 1><<<grid, 256, 0, stream>>>(V, wcb, bc, out);
    } else {
        // 8 MB path: no xb; GEMM1 converts x f32->bf16 during staging
        __hip_bfloat16* wvb = (__hip_bfloat16*)d_ws;
        __hip_bfloat16* wcb = wvb + WE;
        __hip_bfloat16* V   = wcb + WE;
        cvt3_kernel<<<(int)(2 * (WE / 8) / 256), 256, 0, stream>>>(
            x, wv, wc, nullptr, wvb, wcb, 0);
        gemm_kernel<true, 0><<<grid, 256, 0, stream>>>(x, wvb, nullptr, V);
        quantum_kernel<<<(int)(XE / 8 / 256), 256, 0, stream>>>(V, rx);
        gemm_kernel<false, 1><<<grid, 256, 0, stream>>>(V, wcb, bc, out);
    }
}